// Round 1
// baseline (48.385 us; speedup 1.0000x reference)
//
#include <hip/hip_runtime.h>
#include <math.h>

// Problem constants (match reference)
#define NB 32
#define NA 5
#define NC 20
#define NG 19
#define NT 256
#define GG  (NG*NG)                 // 361
#define CELLS (NB*NA*NG*NG)         // 57760
#define K2BLK ((CELLS + 255)/256)   // 226

#define OBJECT_SCALE   5.0f
#define NOOBJ_SCALE    1.0f
#define CLASS_SCALE    1.0f
#define COORD_SCALE    1.0f
#define THRESH         0.6f

__constant__ float c_aw[5] = {1.3221f, 3.19275f, 5.05587f, 9.47112f, 11.2364f};
__constant__ float c_ah[5] = {1.73145f, 4.00944f, 8.09892f, 4.84053f, 10.0071f};

__device__ __forceinline__ float sigm(float v) { return 1.f / (1.f + expf(-v)); }

// ---- workspace layout (float offsets) ----
#define SUMS_OFF 0      // 3 floats: cls_sum, obj_sum, coord_sum
#define FIDX_OFF 16     // 256 ints: target flat index (b,a,gy,gx)
#define X1_OFF   272    // 256 floats each: target box corners + area
#define Y1_OFF   528
#define X2_OFF   784
#define Y2_OFF   1040
#define AREA_OFF 1296
#define PART_OFF 1552   // K2BLK*4 floats: per-block (noobj_sum, noobj_cnt, prior_sum, nm_cnt)

// ---------------- Kernel 1: per-target losses + target records ----------------
__global__ __launch_bounds__(256)
void k_targets(const float* __restrict__ x, const float* __restrict__ tg,
               float* __restrict__ ws_f, int* __restrict__ ws_i) {
    int t = threadIdx.x;   // exactly NT threads

    // load target row
    float sif = tg[t*6+0], cif = tg[t*6+1];
    float gx_f = tg[t*6+2] * NG, gy_f = tg[t*6+3] * NG;
    float gw = tg[t*6+4] * NG, gh = tg[t*6+5] * NG;

    // anchor argmax via wh-iou (first-max tie-break)
    int ai = 0; float best = -1.f;
    #pragma unroll
    for (int a = 0; a < NA; ++a) {
        float inter = fminf(c_aw[a], gw) * fminf(c_ah[a], gh);
        float uni   = c_aw[a]*c_ah[a] + gw*gh - inter;
        float iou   = inter / uni;
        if (iou > best) { best = iou; ai = a; }
    }
    int si = (int)sif, ci = (int)cif;
    int gxi = (int)gx_f, gyi = (int)gy_f;

    int base = ((si*NA + ai)*(NC+5))*GG + gyi*NG + gxi;  // channel stride = GG
    float txv = x[base + 0*GG];
    float tyv = x[base + 1*GG];
    float twv = x[base + 2*GG];
    float thv = x[base + 3*GG];
    float cfv = x[base + 4*GG];

    float sx = sigm(txv), sy = sigm(tyv);
    float aw = c_aw[ai], ah = c_ah[ai];
    float pw = expf(twv) * aw, ph = expf(thv) * ah;

    // pred box (center) vs target box (center), both in grid units
    float pcx = sx + (float)gxi, pcy = sy + (float)gyi;
    float px1 = pcx - pw*0.5f, px2 = pcx + pw*0.5f;
    float py1 = pcy - ph*0.5f, py2 = pcy + ph*0.5f;
    float tx1 = gx_f - gw*0.5f, tx2 = gx_f + gw*0.5f;
    float ty1 = gy_f - gh*0.5f, ty2 = gy_f + gh*0.5f;
    float iw = fmaxf(0.f, fminf(px2, tx2) - fmaxf(px1, tx1));
    float ih = fmaxf(0.f, fminf(py2, ty2) - fmaxf(py1, ty1));
    float inter = iw * ih;
    float uni = pw*ph + gw*gh - inter;
    float iou = inter / (uni + 1e-16f);

    float pconf = sigm(cfv);
    float dobj = pconf - iou;
    float s_obj = dobj * dobj;

    float s_cls = 0.f;
    for (int c = 0; c < NC; ++c) {
        float pc = sigm(x[base + (5 + c)*GG]);
        float d = pc - ((c == ci) ? 1.f : 0.f);
        s_cls += d * d;
    }

    float scl = sqrtf(2.f - gw*gh / (float)(NG*NG));
    float d0 = (sx - (gx_f - (float)gxi)) * scl;
    float d1 = (sy - (gy_f - (float)gyi)) * scl;
    float d2 = (twv - logf(gw / aw)) * scl;
    float d3 = (thv - logf(gh / ah)) * scl;
    float s_crd = d0*d0 + d1*d1 + d2*d2 + d3*d3;

    // target record for kernel 2
    ws_i[FIDX_OFF + t] = ((si*NA + ai)*NG + gyi)*NG + gxi;
    ws_f[X1_OFF   + t] = tx1;
    ws_f[Y1_OFF   + t] = ty1;
    ws_f[X2_OFF   + t] = tx2;
    ws_f[Y2_OFF   + t] = ty2;
    ws_f[AREA_OFF + t] = gw * gh;

    // deterministic block tree-reduce of the 3 sums
    __shared__ float r0[256], r1[256], r2[256];
    r0[t] = s_cls; r1[t] = s_obj; r2[t] = s_crd;
    __syncthreads();
    for (int s = 128; s > 0; s >>= 1) {
        if (t < s) { r0[t] += r0[t+s]; r1[t] += r1[t+s]; r2[t] += r2[t+s]; }
        __syncthreads();
    }
    if (t == 0) {
        ws_f[SUMS_OFF + 0] = r0[0];
        ws_f[SUMS_OFF + 1] = r1[0];
        ws_f[SUMS_OFF + 2] = r2[0];
    }
}

// ---------------- Kernel 2: per-cell noobj / prior accumulation ----------------
__global__ __launch_bounds__(256)
void k_cells(const float* __restrict__ x, const float* __restrict__ ws_f,
             const int* __restrict__ ws_i, float* __restrict__ partials) {
    __shared__ int   sfid[NT];
    __shared__ float sx1[NT], sy1[NT], sx2[NT], sy2[NT], sar[NT];
    int t = threadIdx.x;
    sfid[t] = ws_i[FIDX_OFF + t];
    sx1[t] = ws_f[X1_OFF + t];
    sy1[t] = ws_f[Y1_OFF + t];
    sx2[t] = ws_f[X2_OFF + t];
    sy2[t] = ws_f[Y2_OFF + t];
    sar[t] = ws_f[AREA_OFF + t];
    __syncthreads();

    int idx = blockIdx.x * 256 + t;
    float v_no = 0.f, v_nc = 0.f, v_pr = 0.f, v_nm = 0.f;
    if (idx < CELLS) {
        int gx = idx % NG;
        int r  = idx / NG;
        int gy = r % NG;  r /= NG;
        int a  = r % NA;
        int b  = r / NA;

        int base = ((b*NA + a)*(NC+5))*GG + gy*NG + gx;
        float txv = x[base + 0*GG];
        float tyv = x[base + 1*GG];
        float twv = x[base + 2*GG];
        float thv = x[base + 3*GG];
        float cfv = x[base + 4*GG];

        float sx = sigm(txv), sy = sigm(tyv);
        float pw = expf(twv) * c_aw[a], ph = expf(thv) * c_ah[a];
        float cx = sx + (float)gx, cy = sy + (float)gy;
        float bx1 = cx - pw*0.5f, bx2 = cx + pw*0.5f;
        float by1 = cy - ph*0.5f, by2 = cy + ph*0.5f;
        float area1 = pw * ph;

        float mx = 0.f;
        bool is_t = false;
        #pragma unroll 4
        for (int j = 0; j < NT; ++j) {
            float iw = fmaxf(0.f, fminf(bx2, sx2[j]) - fmaxf(bx1, sx1[j]));
            float ih = fmaxf(0.f, fminf(by2, sy2[j]) - fmaxf(by1, sy1[j]));
            float inter = iw * ih;
            float uni = area1 + sar[j] - inter;
            float iou = inter / (uni + 1e-16f);
            mx = fmaxf(mx, iou);
            is_t = is_t || (sfid[j] == idx);
        }

        if (!is_t) {
            v_nm = 1.f;
            float e0 = sx - 0.5f, e1 = sy - 0.5f;
            v_pr = e0*e0 + e1*e1 + twv*twv + thv*thv;
            if (mx <= THRESH) {
                float pconf = sigm(cfv);
                v_no = pconf * pconf;
                v_nc = 1.f;
            }
        }
    }

    __shared__ float r0[256], r1[256], r2[256], r3[256];
    r0[t] = v_no; r1[t] = v_nc; r2[t] = v_pr; r3[t] = v_nm;
    __syncthreads();
    for (int s = 128; s > 0; s >>= 1) {
        if (t < s) { r0[t]+=r0[t+s]; r1[t]+=r1[t+s]; r2[t]+=r2[t+s]; r3[t]+=r3[t+s]; }
        __syncthreads();
    }
    if (t == 0) {
        partials[blockIdx.x*4 + 0] = r0[0];
        partials[blockIdx.x*4 + 1] = r1[0];
        partials[blockIdx.x*4 + 2] = r2[0];
        partials[blockIdx.x*4 + 3] = r3[0];
    }
}

// ---------------- Kernel 3: final deterministic combine ----------------
__global__ __launch_bounds__(256)
void k_final(const float* __restrict__ ws_f, const float* __restrict__ partials,
             const int* __restrict__ seen, float* __restrict__ out) {
    int t = threadIdx.x;
    float a0 = 0.f, a1 = 0.f, a2 = 0.f, a3 = 0.f;
    for (int j = t; j < K2BLK; j += 256) {
        a0 += partials[j*4 + 0];
        a1 += partials[j*4 + 1];
        a2 += partials[j*4 + 2];
        a3 += partials[j*4 + 3];
    }
    __shared__ float r0[256], r1[256], r2[256], r3[256];
    r0[t] = a0; r1[t] = a1; r2[t] = a2; r3[t] = a3;
    __syncthreads();
    for (int s = 128; s > 0; s >>= 1) {
        if (t < s) { r0[t]+=r0[t+s]; r1[t]+=r1[t+s]; r2[t]+=r2[t+s]; r3[t]+=r3[t+s]; }
        __syncthreads();
    }
    if (t == 0) {
        float loss_cls = ws_f[SUMS_OFF + 0] / (float)(NT * NC) * CLASS_SCALE;
        float loss_obj = ws_f[SUMS_OFF + 1] / (float)NT * OBJECT_SCALE;
        float loss_crd = ws_f[SUMS_OFF + 2] / (float)(NT * 4) * COORD_SCALE;
        float loss_no  = r0[0] / r1[0] * NOOBJ_SCALE;
        float total = loss_cls + loss_obj + loss_crd + loss_no;
        if (seen[0] < 12800) {
            total += r2[0] / (r3[0] * 4.f) * 0.01f;
        }
        out[0] = total;
    }
}

extern "C" void kernel_launch(void* const* d_in, const int* in_sizes, int n_in,
                              void* d_out, int out_size, void* d_ws, size_t ws_size,
                              hipStream_t stream) {
    const float* x    = (const float*)d_in[0];
    const float* tg   = (const float*)d_in[1];
    const int*   seen = (const int*)d_in[2];
    float* out  = (float*)d_out;
    float* ws_f = (float*)d_ws;
    int*   ws_i = (int*)d_ws;
    float* partials = ws_f + PART_OFF;

    k_targets<<<1, 256, 0, stream>>>(x, tg, ws_f, ws_i);
    k_cells<<<K2BLK, 256, 0, stream>>>(x, ws_f, ws_i, partials);
    k_final<<<1, 256, 0, stream>>>(ws_f, partials, seen, out);
}

// Round 2
// 24.651 us; speedup vs baseline: 1.9628x; 1.9628x over previous
//
#include <hip/hip_runtime.h>
#include <math.h>

// Problem constants (match reference)
#define NB 32
#define NA 5
#define NC 20
#define NG 19
#define NT 256
#define GG  (NG*NG)                  // 361
#define CELLS (NB*NA*NG*NG)          // 57760
#define CPB 64                       // cells per block (one lane per cell)
#define NBLK ((CELLS + CPB - 1)/CPB) // 903

#define OBJECT_SCALE   5.0f
#define NOOBJ_SCALE    1.0f
#define CLASS_SCALE    1.0f
#define COORD_SCALE    1.0f

__constant__ float c_aw[5] = {1.3221f, 3.19275f, 5.05587f, 9.47112f, 11.2364f};
__constant__ float c_ah[5] = {1.73145f, 4.00944f, 8.09892f, 4.84053f, 10.0071f};

__device__ __forceinline__ float sigm(float v) { return 1.f / (1.f + expf(-v)); }

// ---- workspace layout (float offsets) ----
#define SUMS_OFF 0      // 3 floats: cls_sum, obj_sum, coord_sum (written by block 0)
#define PART_OFF 16     // NBLK*4 floats: (noobj_sum, noobj_cnt, prior_sum, nm_cnt)

// ================= Kernel A: everything except the final combine =================
// Grid: NBLK blocks x 256 threads (4 waves). Each block owns 64 cells.
// Wave w scans target slice j = 4*i + w (wave-uniform LDS broadcast reads).
// Block 0 additionally computes the per-target cls/obj/coord sums.
__global__ __launch_bounds__(256)
void k_main(const float* __restrict__ x, const float* __restrict__ tg,
            float* __restrict__ ws_f, float* __restrict__ partials) {
    __shared__ float4 s_corn[NT];   // target box corners (x1,y1,x2,y2) in grid units
    __shared__ float  s_s06[NT];    // 0.6 * target area
    __shared__ int    s_mask[CPB];  // 1 if this block-local cell is a target cell
    __shared__ float  s_pm[4][CPB]; // per-wave partial max metric
    __shared__ float  s_wred[12];   // block-0 cross-wave reduce (3 sums x 4 waves)

    const int t = threadIdx.x;
    const int wave = t >> 6, lane = t & 63;
    const int cellBase = blockIdx.x * CPB;

    // ---------- stage targets (every thread handles target t) ----------
    float gxf = tg[t*6+2] * NG, gyf = tg[t*6+3] * NG;
    float gw  = tg[t*6+4] * NG, gh  = tg[t*6+5] * NG;
    const int si = (int)tg[t*6+0];
    const int ci = (int)tg[t*6+1];
    int ai = 0;
    {
        float best = -1.f;
        #pragma unroll
        for (int a = 0; a < NA; ++a) {
            float inter = fminf(c_aw[a], gw) * fminf(c_ah[a], gh);
            float uni   = c_aw[a]*c_ah[a] + gw*gh - inter;
            float iou   = inter / uni;
            if (iou > best) { best = iou; ai = a; }
        }
    }
    const int gxi = (int)gxf, gyi = (int)gyf;
    const int fid = ((si*NA + ai)*NG + gyi)*NG + gxi;
    {
        float hw = gw*0.5f, hh = gh*0.5f;
        s_corn[t] = make_float4(gxf - hw, gyf - hh, gxf + hw, gyf + hh);
        s_s06[t]  = 0.6f * (gw * gh);
        if (t < CPB) s_mask[t] = 0;
    }
    __syncthreads();
    {
        int rel = fid - cellBase;
        if (rel >= 0 && rel < CPB) s_mask[rel] = 1;  // races write same value
    }

    // ---------- decode my cell (lane = block-local cell; all 4 waves decode) ----------
    const int idx = cellBase + lane;
    const bool valid = idx < CELLS;
    float bx1 = 0.f, by1 = 0.f, bx2 = 0.f, by2 = 0.f, cthr = 0.f;
    float sx = 0.f, sy = 0.f, twv = 0.f, thv = 0.f, cfv = 0.f;
    if (valid) {
        int gx = idx % NG;
        int r  = idx / NG;
        int gy = r % NG;  r /= NG;
        int a  = r % NA;
        int b  = r / NA;
        int base = ((b*NA + a)*(NC+5))*GG + gy*NG + gx;
        float txv = x[base + 0*GG];
        float tyv = x[base + 1*GG];
        twv = x[base + 2*GG];
        thv = x[base + 3*GG];
        cfv = x[base + 4*GG];
        sx = sigm(txv); sy = sigm(tyv);
        float pw = expf(twv) * c_aw[a], ph = expf(thv) * c_ah[a];
        float cx = sx + (float)gx, cy = sy + (float)gy;
        bx1 = cx - pw*0.5f; bx2 = cx + pw*0.5f;
        by1 = cy - ph*0.5f; by2 = cy + ph*0.5f;
        cthr = 0.6f * (pw * ph) + 6e-17f;   // 0.6*(area_p + 1e-16)
    }
    __syncthreads();  // staging + mask complete

    // ---------- main loop: 64 targets per wave, wave-uniform broadcast reads ----------
    float m = -1e30f;
    #pragma unroll 8
    for (int i = 0; i < 64; ++i) {
        int j = (i << 2) | wave;
        float4 tb = s_corn[j];
        float s06 = s_s06[j];
        float iw = fminf(bx2, tb.z) - fmaxf(bx1, tb.x);
        float ih = fminf(by2, tb.w) - fmaxf(by1, tb.y);
        iw = fmaxf(iw, 0.f); ih = fmaxf(ih, 0.f);
        float inter = iw * ih;
        // any-IoU>0.6  <=>  max_j(1.6*inter - 0.6*area_t) > 0.6*area_p + 6e-17
        m = fmaxf(m, fmaf(1.6f, inter, -s06));
    }
    s_pm[wave][lane] = m;
    __syncthreads();

    // ---------- epilogue: wave 0 combines + accumulates per-block partials ----------
    if (wave == 0) {
        float mm = fmaxf(fmaxf(s_pm[0][lane], s_pm[1][lane]),
                         fmaxf(s_pm[2][lane], s_pm[3][lane]));
        float v_no = 0.f, v_nc = 0.f, v_pr = 0.f, v_nm = 0.f;
        if (valid && !s_mask[lane]) {
            v_nm = 1.f;
            float e0 = sx - 0.5f, e1 = sy - 0.5f;
            v_pr = e0*e0 + e1*e1 + twv*twv + thv*thv;
            if (!(mm > cthr)) {          // max_iou <= 0.6
                float pc = sigm(cfv);
                v_no = pc * pc;
                v_nc = 1.f;
            }
        }
        #pragma unroll
        for (int off = 32; off > 0; off >>= 1) {
            v_no += __shfl_down(v_no, off);
            v_nc += __shfl_down(v_nc, off);
            v_pr += __shfl_down(v_pr, off);
            v_nm += __shfl_down(v_nm, off);
        }
        if (lane == 0) {
            partials[blockIdx.x*4 + 0] = v_no;
            partials[blockIdx.x*4 + 1] = v_nc;
            partials[blockIdx.x*4 + 2] = v_pr;
            partials[blockIdx.x*4 + 3] = v_nm;
        }
    }

    // ---------- block 0 only: per-target cls/obj/coord losses ----------
    if (blockIdx.x == 0) {
        int base = ((si*NA + ai)*(NC+5))*GG + gyi*NG + gxi;
        float txv = x[base + 0*GG];
        float tyv = x[base + 1*GG];
        float twt = x[base + 2*GG];
        float tht = x[base + 3*GG];
        float cft = x[base + 4*GG];
        float tsx = sigm(txv), tsy = sigm(tyv);
        float aw = c_aw[ai], ah = c_ah[ai];
        float pw = expf(twt) * aw, ph = expf(tht) * ah;

        float pcx = tsx + (float)gxi, pcy = tsy + (float)gyi;
        float px1 = pcx - pw*0.5f, px2 = pcx + pw*0.5f;
        float py1 = pcy - ph*0.5f, py2 = pcy + ph*0.5f;
        float hw = gw*0.5f, hh = gh*0.5f;
        float iw = fmaxf(0.f, fminf(px2, gxf + hw) - fmaxf(px1, gxf - hw));
        float ih = fmaxf(0.f, fminf(py2, gyf + hh) - fmaxf(py1, gyf - hh));
        float inter = iw * ih;
        float uni = pw*ph + gw*gh - inter;
        float iou = inter / (uni + 1e-16f);

        float pconf = sigm(cft);
        float dobj = pconf - iou;
        float s_obj = dobj * dobj;

        float s_cls = 0.f;
        for (int cc = 0; cc < NC; ++cc) {
            float pc = sigm(x[base + (5 + cc)*GG]);
            float d = pc - ((cc == ci) ? 1.f : 0.f);
            s_cls += d * d;
        }

        float scl = sqrtf(2.f - gw*gh / (float)(NG*NG));
        float d0 = (tsx - (gxf - (float)gxi)) * scl;
        float d1 = (tsy - (gyf - (float)gyi)) * scl;
        float d2 = (twt - logf(gw / aw)) * scl;
        float d3 = (tht - logf(gh / ah)) * scl;
        float s_crd = d0*d0 + d1*d1 + d2*d2 + d3*d3;

        // wave shfl-reduce, then cross-wave via LDS
        #pragma unroll
        for (int off = 32; off > 0; off >>= 1) {
            s_cls += __shfl_down(s_cls, off);
            s_obj += __shfl_down(s_obj, off);
            s_crd += __shfl_down(s_crd, off);
        }
        if (lane == 0) {
            s_wred[wave*3 + 0] = s_cls;
            s_wred[wave*3 + 1] = s_obj;
            s_wred[wave*3 + 2] = s_crd;
        }
        __syncthreads();
        if (t == 0) {
            ws_f[SUMS_OFF + 0] = s_wred[0] + s_wred[3] + s_wred[6] + s_wred[9];
            ws_f[SUMS_OFF + 1] = s_wred[1] + s_wred[4] + s_wred[7] + s_wred[10];
            ws_f[SUMS_OFF + 2] = s_wred[2] + s_wred[5] + s_wred[8] + s_wred[11];
        }
    }
}

// ================= Kernel B: final deterministic combine =================
__global__ __launch_bounds__(256)
void k_final(const float* __restrict__ ws_f, const float* __restrict__ partials,
             const int* __restrict__ seen, float* __restrict__ out) {
    int t = threadIdx.x;
    float a0 = 0.f, a1 = 0.f, a2 = 0.f, a3 = 0.f;
    for (int j = t; j < NBLK; j += 256) {
        a0 += partials[j*4 + 0];
        a1 += partials[j*4 + 1];
        a2 += partials[j*4 + 2];
        a3 += partials[j*4 + 3];
    }
    __shared__ float r0[256], r1[256], r2[256], r3[256];
    r0[t] = a0; r1[t] = a1; r2[t] = a2; r3[t] = a3;
    __syncthreads();
    for (int s = 128; s > 0; s >>= 1) {
        if (t < s) { r0[t]+=r0[t+s]; r1[t]+=r1[t+s]; r2[t]+=r2[t+s]; r3[t]+=r3[t+s]; }
        __syncthreads();
    }
    if (t == 0) {
        float loss_cls = ws_f[SUMS_OFF + 0] / (float)(NT * NC) * CLASS_SCALE;
        float loss_obj = ws_f[SUMS_OFF + 1] / (float)NT * OBJECT_SCALE;
        float loss_crd = ws_f[SUMS_OFF + 2] / (float)(NT * 4) * COORD_SCALE;
        float loss_no  = r0[0] / r1[0] * NOOBJ_SCALE;
        float total = loss_cls + loss_obj + loss_crd + loss_no;
        if (seen[0] < 12800) {
            total += r2[0] / (r3[0] * 4.f) * 0.01f;
        }
        out[0] = total;
    }
}

extern "C" void kernel_launch(void* const* d_in, const int* in_sizes, int n_in,
                              void* d_out, int out_size, void* d_ws, size_t ws_size,
                              hipStream_t stream) {
    const float* x    = (const float*)d_in[0];
    const float* tg   = (const float*)d_in[1];
    const int*   seen = (const int*)d_in[2];
    float* out  = (float*)d_out;
    float* ws_f = (float*)d_ws;
    float* partials = ws_f + PART_OFF;

    k_main<<<NBLK, 256, 0, stream>>>(x, tg, ws_f, partials);
    k_final<<<1, 256, 0, stream>>>(ws_f, partials, seen, out);
}